// Round 1
// baseline (2266.461 us; speedup 1.0000x reference)
//
#include <hip/hip_runtime.h>

#define NNODE 10000
#define NEDGE 160000
#define DD 256

using f32x4  = __attribute__((ext_vector_type(4))) float;
using bf16x8 = __attribute__((ext_vector_type(8))) short;

__device__ inline short f2bf(float f) {
  unsigned u = __float_as_uint(f);
  unsigned r = (u + 0x7fffu + ((u >> 16) & 1u)) >> 16;
  return (short)(unsigned short)r;
}

__global__ void cast_x_kernel(const float* __restrict__ x, short* __restrict__ xb, int total) {
  int i = blockIdx.x * 256 + threadIdx.x;
  if (i < total) xb[i] = f2bf(x[i]);
}

// pack w[K][N] (f32) -> p[(k>>3)][n][k&7] (bf16): lane fragment loads become contiguous 16B
__global__ void pack_w_kernel(const float* __restrict__ w, short* __restrict__ p, int K, int N) {
  int idx = blockIdx.x * 256 + threadIdx.x;
  if (idx >= K * N) return;
  int k = idx / N, n = idx - k * N;
  p[(size_t)(k >> 3) * N * 8 + (size_t)n * 8 + (k & 7)] = f2bf(w[idx]);
}

// MODE 0: edge (K1=768, gather x[i]|x[j]|edge_attr, residual=edge_attr, scatter agg)
// MODE 1: node (K1=512, gather x|agg, residual=x)
template<int MODE>
__global__ __launch_bounds__(256, 2)
void fused_mlp(const float* __restrict__ x,
               const short* __restrict__ xb,
               const int*   __restrict__ ei,
               const float* __restrict__ ea,
               const float* __restrict__ aggr,
               float*       __restrict__ aggw,
               const short* __restrict__ w1p,
               const float* __restrict__ b1,
               const short* __restrict__ w2p,
               const float* __restrict__ b2,
               const float* __restrict__ gam,
               const float* __restrict__ bet,
               float*       __restrict__ out)
{
  constexpr int K1 = (MODE == 0) ? 768 : 512;
  constexpr int AP = 72;   // A-stage pitch (bf16 elems): 144B rows -> 2-way bank alias (free)
  constexpr int HP = 520;  // hidden pitch (bf16): 1040B rows -> 2-way
  constexpr int OP = 264;  // out-tile pitch (f32)

  __shared__ __align__(16) char smem[9728 + 64 * OP * 4];
  short* asb  = (short*)smem;            // [64][72] bf16 A-stage
  int*   idxi = (int*)(smem + 9216);     // [64]
  int*   idxj = idxi + 64;               // [64]
  short* hid  = (short*)(smem + 9728);   // [64][520] bf16 hidden
  float* outt = (float*)(smem + 9728);   // [64][264] f32 (reuses hidden region)

  const int tid  = threadIdx.x;
  const int lane = tid & 63;
  const int wid  = tid >> 6;   // 0..3
  const int m0   = blockIdx.x * 64;
  const int lhi  = lane >> 4;  // 0..3
  const int llo  = lane & 15;  // 0..15

  if (MODE == 0) {
    if (tid < 64) {
      int a = ei[m0 + tid];
      int b = ei[NEDGE + m0 + tid];
      idxi[tid] = min(max(a, 0), NNODE - 1);
      idxj[tid] = min(max(b, 0), NNODE - 1);
    }
  }

  f32x4 acc1[4][8] = {};
  const bf16x8* bp1 = (const bf16x8*)w1p;

  // ---------------- GEMM1: [64 x K1] @ [K1 x 512] ----------------
  for (int k0 = 0; k0 < K1; k0 += 64) {
    __syncthreads();
    #pragma unroll
    for (int it = 0; it < 2; it++) {
      int c = it * 256 + tid;          // 0..511 chunk id (16B each)
      int row = c >> 3, seg = c & 7;
      int gk = k0 + seg * 8;
      bf16x8 v;
      if (MODE == 0) {
        if (gk < 256) {
          v = *(const bf16x8*)(xb + (size_t)idxi[row] * DD + gk);
        } else if (gk < 512) {
          v = *(const bf16x8*)(xb + (size_t)idxj[row] * DD + (gk - 256));
        } else {
          const float* s = ea + (size_t)(m0 + row) * DD + (gk - 512);
          #pragma unroll
          for (int u = 0; u < 8; u++) v[u] = f2bf(s[u]);
        }
      } else {
        int rr = m0 + row; rr = rr < NNODE ? rr : NNODE - 1;
        if (gk < 256) {
          v = *(const bf16x8*)(xb + (size_t)rr * DD + gk);
        } else {
          const float* s = aggr + (size_t)rr * DD + (gk - 256);
          #pragma unroll
          for (int u = 0; u < 8; u++) v[u] = f2bf(s[u]);
        }
      }
      *(bf16x8*)(asb + row * AP + seg * 8) = v;
    }
    __syncthreads();

    #pragma unroll
    for (int kk = 0; kk < 64; kk += 32) {
      bf16x8 a[4];
      #pragma unroll
      for (int mf = 0; mf < 4; mf++)
        a[mf] = *(const bf16x8*)(asb + (mf * 16 + llo) * AP + kk + lhi * 8);
      int kg = ((k0 + kk) >> 3) + lhi;
      #pragma unroll
      for (int nf = 0; nf < 8; nf++) {
        bf16x8 b = bp1[(size_t)kg * 512 + wid * 128 + nf * 16 + llo];
        #pragma unroll
        for (int mf = 0; mf < 4; mf++)
          acc1[mf][nf] = __builtin_amdgcn_mfma_f32_16x16x32_bf16(a[mf], b, acc1[mf][nf], 0, 0, 0);
      }
    }
  }

  // bias + relu -> hidden bf16 in LDS
  #pragma unroll
  for (int nf = 0; nf < 8; nf++) {
    int col = wid * 128 + nf * 16 + llo;
    float bb = b1[col];
    #pragma unroll
    for (int mf = 0; mf < 4; mf++) {
      #pragma unroll
      for (int r = 0; r < 4; r++) {
        float v = acc1[mf][nf][r] + bb;
        v = v > 0.f ? v : 0.f;
        hid[(mf * 16 + lhi * 4 + r) * HP + col] = f2bf(v);
      }
    }
  }
  __syncthreads();

  // ---------------- GEMM2: [64 x 512] @ [512 x 256] ----------------
  f32x4 acc2[4][4] = {};
  const bf16x8* bp2 = (const bf16x8*)w2p;
  #pragma unroll 4
  for (int kk = 0; kk < 512; kk += 32) {
    bf16x8 a[4];
    #pragma unroll
    for (int mf = 0; mf < 4; mf++)
      a[mf] = *(const bf16x8*)(hid + (mf * 16 + llo) * HP + kk + lhi * 8);
    int kg = (kk >> 3) + lhi;
    #pragma unroll
    for (int nf = 0; nf < 4; nf++) {
      bf16x8 b = bp2[(size_t)kg * 256 + wid * 64 + nf * 16 + llo];
      #pragma unroll
      for (int mf = 0; mf < 4; mf++)
        acc2[mf][nf] = __builtin_amdgcn_mfma_f32_16x16x32_bf16(a[mf], b, acc2[mf][nf], 0, 0, 0);
    }
  }
  __syncthreads();  // everyone done reading hid

  #pragma unroll
  for (int nf = 0; nf < 4; nf++) {
    int col = wid * 64 + nf * 16 + llo;
    float bb = b2[col];
    #pragma unroll
    for (int mf = 0; mf < 4; mf++) {
      #pragma unroll
      for (int r = 0; r < 4; r++)
        outt[(mf * 16 + lhi * 4 + r) * OP + col] = acc2[mf][nf][r] + bb;
    }
  }
  __syncthreads();

  // ---------------- LayerNorm + residual + store (+ scatter) ----------------
  int r = tid >> 2;   // row 0..63
  int s = tid & 3;    // quarter 0..3 (64 cols each)
  const float* rowp = outt + r * OP + s * 64;
  float sum = 0.f, sq = 0.f;
  #pragma unroll 8
  for (int c = 0; c < 64; c++) { float v = rowp[c]; sum += v; sq += v * v; }
  sum += __shfl_xor(sum, 1); sq += __shfl_xor(sq, 1);
  sum += __shfl_xor(sum, 2); sq += __shfl_xor(sq, 2);
  float mu  = sum * (1.f / 256.f);
  float var = sq  * (1.f / 256.f) - mu * mu;
  float rs  = rsqrtf(var + 1e-5f);

  int grow = m0 + r;
  if (MODE == 1 && grow >= NNODE) return;
  const float* resid = (MODE == 0 ? ea : x) + (size_t)grow * DD + s * 64;
  float* op = out + (size_t)grow * DD + s * 64;
  float* ap = (MODE == 0) ? (aggw + (size_t)idxj[r] * DD + s * 64) : nullptr;

  const float4* resid4 = (const float4*)resid;
  const float4* gam4   = (const float4*)(gam + s * 64);
  const float4* bet4   = (const float4*)(bet + s * 64);
  float4* op4 = (float4*)op;
  #pragma unroll 4
  for (int c4 = 0; c4 < 16; c4++) {
    float4 rv = resid4[c4];
    float4 gv = gam4[c4];
    float4 bv = bet4[c4];
    float4 ov;
    ov.x = (rowp[c4*4+0] - mu) * rs * gv.x + bv.x + rv.x;
    ov.y = (rowp[c4*4+1] - mu) * rs * gv.y + bv.y + rv.y;
    ov.z = (rowp[c4*4+2] - mu) * rs * gv.z + bv.z + rv.z;
    ov.w = (rowp[c4*4+3] - mu) * rs * gv.w + bv.w + rv.w;
    op4[c4] = ov;
    if (MODE == 0) {
      atomicAdd(ap + c4*4 + 0, ov.x);
      atomicAdd(ap + c4*4 + 1, ov.y);
      atomicAdd(ap + c4*4 + 2, ov.z);
      atomicAdd(ap + c4*4 + 3, ov.w);
    }
  }
}

extern "C" void kernel_launch(void* const* d_in, const int* in_sizes, int n_in,
                              void* d_out, int out_size, void* d_ws, size_t ws_size,
                              hipStream_t stream) {
  const float* x      = (const float*)d_in[0];
  const int*   ei     = (const int*)  d_in[1];
  const float* ea     = (const float*)d_in[2];
  const float* e_w1   = (const float*)d_in[3];
  const float* e_b1   = (const float*)d_in[4];
  const float* e_w2   = (const float*)d_in[5];
  const float* e_b2   = (const float*)d_in[6];
  const float* e_g    = (const float*)d_in[7];
  const float* e_beta = (const float*)d_in[8];
  const float* n_w1   = (const float*)d_in[9];
  const float* n_b1   = (const float*)d_in[10];
  const float* n_w2   = (const float*)d_in[11];
  const float* n_b2   = (const float*)d_in[12];
  const float* n_g    = (const float*)d_in[13];
  const float* n_beta = (const float*)d_in[14];

  float* out_x = (float*)d_out;                       // [N, 256]
  float* out_e = (float*)d_out + (size_t)NNODE * DD;  // [E, 256]

  char* w = (char*)d_ws;
  short* xb   = (short*)(w);                 // 5,120,000 B
  short* ew1p = (short*)(w + 5120000);       //   786,432 B
  short* nw1p = (short*)(w + 5906432);       //   524,288 B
  short* ew2p = (short*)(w + 6430720);       //   262,144 B
  short* nw2p = (short*)(w + 6692864);       //   262,144 B
  float* agg  = (float*)(w + 6955008);       // 10,240,000 B  (total ~17.2 MB)

  hipMemsetAsync(agg, 0, (size_t)NNODE * DD * sizeof(float), stream);
  cast_x_kernel<<<(NNODE * DD + 255) / 256, 256, 0, stream>>>(x, xb, NNODE * DD);
  pack_w_kernel<<<(768 * 512 + 255) / 256, 256, 0, stream>>>(e_w1, ew1p, 768, 512);
  pack_w_kernel<<<(512 * 512 + 255) / 256, 256, 0, stream>>>(n_w1, nw1p, 512, 512);
  pack_w_kernel<<<(512 * 256 + 255) / 256, 256, 0, stream>>>(e_w2, ew2p, 512, 256);
  pack_w_kernel<<<(512 * 256 + 255) / 256, 256, 0, stream>>>(n_w2, nw2p, 512, 256);

  fused_mlp<0><<<NEDGE / 64, 256, 0, stream>>>(x, xb, ei, ea, agg, agg,
                                               ew1p, e_b1, ew2p, e_b2, e_g, e_beta, out_e);
  fused_mlp<1><<<(NNODE + 63) / 64, 256, 0, stream>>>(x, xb, ei, ea, agg, agg,
                                                      nw1p, n_b1, nw2p, n_b2, n_g, n_beta, out_x);
}

// Round 2
// 553.531 us; speedup vs baseline: 4.0946x; 4.0946x over previous
//
#include <hip/hip_runtime.h>

#define NNODE 10000
#define NEDGE 160000
#define DD 256

using f32x4  = __attribute__((ext_vector_type(4))) float;
using bf16x8 = __attribute__((ext_vector_type(8))) short;

__device__ inline short f2bf(float f) {
  unsigned u = __float_as_uint(f);
  unsigned r = (u + 0x7fffu + ((u >> 16) & 1u)) >> 16;
  return (short)(unsigned short)r;
}

__global__ void cast_x_kernel(const float* __restrict__ x, short* __restrict__ xb, int total) {
  int i = blockIdx.x * 256 + threadIdx.x;
  if (i < total) xb[i] = f2bf(x[i]);
}

// pack w[K][N] (f32) -> p[(k>>3)][n][k&7] (bf16): lane fragment loads become contiguous 16B
__global__ void pack_w_kernel(const float* __restrict__ w, short* __restrict__ p, int K, int N) {
  int idx = blockIdx.x * 256 + threadIdx.x;
  if (idx >= K * N) return;
  int k = idx / N, n = idx - k * N;
  p[(size_t)(k >> 3) * N * 8 + (size_t)n * 8 + (k & 7)] = f2bf(w[idx]);
}

// ---------------- CSR build ----------------
__global__ void hist_kernel(const int* __restrict__ ei, int* __restrict__ deg) {
  int e = blockIdx.x * 256 + threadIdx.x;
  if (e < NEDGE) {
    int j = ei[NEDGE + e]; j = min(max(j, 0), NNODE - 1);
    atomicAdd(&deg[j], 1);
  }
}

__global__ void scan_kernel(const int* __restrict__ deg, int* __restrict__ row_start) {
  __shared__ int part[256];
  int t = threadIdx.x;
  const int CH = 40;  // 256*40 = 10240 >= NNODE
  int base = t * CH;
  int s = 0;
  for (int i = 0; i < CH; i++) {
    int idx = base + i;
    s += (idx < NNODE) ? deg[idx] : 0;
  }
  part[t] = s;
  __syncthreads();
  for (int off = 1; off < 256; off <<= 1) {
    int v = (t >= off) ? part[t - off] : 0;
    __syncthreads();
    part[t] += v;
    __syncthreads();
  }
  int run = (t == 0) ? 0 : part[t - 1];
  for (int i = 0; i < CH; i++) {
    int idx = base + i;
    if (idx < NNODE) { row_start[idx] = run; run += deg[idx]; }
  }
  if (t == 255) row_start[NNODE] = part[255];
}

__global__ void scatter_kernel(const int* __restrict__ ei, const int* __restrict__ row_start,
                               int* __restrict__ cursor, int* __restrict__ csr) {
  int e = blockIdx.x * 256 + threadIdx.x;
  if (e < NEDGE) {
    int j = ei[NEDGE + e]; j = min(max(j, 0), NNODE - 1);
    int p = atomicAdd(&cursor[j], 1);
    csr[row_start[j] + p] = e;
  }
}

// one wave per node: gather new_edge rows, sum fp32, store bf16 agg
__global__ __launch_bounds__(256) void agg_kernel(const float* __restrict__ out_e,
                                                  const int* __restrict__ row_start,
                                                  const int* __restrict__ csr,
                                                  short* __restrict__ aggb) {
  int node = blockIdx.x * 4 + (threadIdx.x >> 6);
  int lane = threadIdx.x & 63;
  if (node >= NNODE) return;
  int rs = row_start[node], re = row_start[node + 1];
  float4 acc = {0.f, 0.f, 0.f, 0.f};
  for (int k = rs; k < re; k++) {
    int eid = csr[k];
    float4 v = *(const float4*)(out_e + (size_t)eid * DD + lane * 4);
    acc.x += v.x; acc.y += v.y; acc.z += v.z; acc.w += v.w;
  }
  short4 o;
  o.x = f2bf(acc.x); o.y = f2bf(acc.y); o.z = f2bf(acc.z); o.w = f2bf(acc.w);
  *(short4*)(aggb + (size_t)node * DD + lane * 4) = o;
}

// MODE 0: edge (K1=768, gather x[i]|x[j]|edge_attr, residual=edge_attr)
// MODE 1: node (K1=512, gather x|agg(bf16), residual=x)
template<int MODE>
__global__ __launch_bounds__(256, 2)
void fused_mlp(const float* __restrict__ x,
               const short* __restrict__ xb,
               const int*   __restrict__ ei,
               const float* __restrict__ ea,
               const short* __restrict__ aggb,
               const short* __restrict__ w1p,
               const float* __restrict__ b1,
               const short* __restrict__ w2p,
               const float* __restrict__ b2,
               const float* __restrict__ gam,
               const float* __restrict__ bet,
               float*       __restrict__ out)
{
  constexpr int K1 = (MODE == 0) ? 768 : 512;
  constexpr int AP = 72;   // A-stage pitch (bf16 elems): 2-way bank alias (free)
  constexpr int HP = 520;  // hidden pitch (bf16)
  constexpr int OP = 264;  // out-tile pitch (f32)

  __shared__ __align__(16) char smem[9728 + 64 * OP * 4];
  short* asb  = (short*)smem;            // [64][72] bf16 A-stage
  int*   idxi = (int*)(smem + 9216);     // [64]
  int*   idxj = idxi + 64;               // [64]
  short* hid  = (short*)(smem + 9728);   // [64][520] bf16 hidden
  float* outt = (float*)(smem + 9728);   // [64][264] f32 (reuses hidden region)

  const int tid  = threadIdx.x;
  const int lane = tid & 63;
  const int wid  = tid >> 6;   // 0..3
  const int m0   = blockIdx.x * 64;
  const int lhi  = lane >> 4;  // 0..3
  const int llo  = lane & 15;  // 0..15

  if (MODE == 0) {
    if (tid < 64) {
      int a = ei[m0 + tid];
      int b = ei[NEDGE + m0 + tid];
      idxi[tid] = min(max(a, 0), NNODE - 1);
      idxj[tid] = min(max(b, 0), NNODE - 1);
    }
  }

  f32x4 acc1[4][8] = {};
  const bf16x8* bp1 = (const bf16x8*)w1p;

  // ---------------- GEMM1: [64 x K1] @ [K1 x 512] ----------------
  for (int k0 = 0; k0 < K1; k0 += 64) {
    __syncthreads();
    #pragma unroll
    for (int it = 0; it < 2; it++) {
      int c = it * 256 + tid;          // 0..511 chunk id (16B each)
      int row = c >> 3, seg = c & 7;
      int gk = k0 + seg * 8;
      bf16x8 v;
      if (MODE == 0) {
        if (gk < 256) {
          v = *(const bf16x8*)(xb + (size_t)idxi[row] * DD + gk);
        } else if (gk < 512) {
          v = *(const bf16x8*)(xb + (size_t)idxj[row] * DD + (gk - 256));
        } else {
          const float4* s = (const float4*)(ea + (size_t)(m0 + row) * DD + (gk - 512));
          float4 v0 = s[0], v1 = s[1];
          v[0] = f2bf(v0.x); v[1] = f2bf(v0.y); v[2] = f2bf(v0.z); v[3] = f2bf(v0.w);
          v[4] = f2bf(v1.x); v[5] = f2bf(v1.y); v[6] = f2bf(v1.z); v[7] = f2bf(v1.w);
        }
      } else {
        int rr = m0 + row; rr = rr < NNODE ? rr : NNODE - 1;
        if (gk < 256) {
          v = *(const bf16x8*)(xb + (size_t)rr * DD + gk);
        } else {
          v = *(const bf16x8*)(aggb + (size_t)rr * DD + (gk - 256));
        }
      }
      *(bf16x8*)(asb + row * AP + seg * 8) = v;
    }
    __syncthreads();

    #pragma unroll
    for (int kk = 0; kk < 64; kk += 32) {
      bf16x8 a[4];
      #pragma unroll
      for (int mf = 0; mf < 4; mf++)
        a[mf] = *(const bf16x8*)(asb + (mf * 16 + llo) * AP + kk + lhi * 8);
      int kg = ((k0 + kk) >> 3) + lhi;
      #pragma unroll
      for (int nf = 0; nf < 8; nf++) {
        bf16x8 b = bp1[(size_t)kg * 512 + wid * 128 + nf * 16 + llo];
        #pragma unroll
        for (int mf = 0; mf < 4; mf++)
          acc1[mf][nf] = __builtin_amdgcn_mfma_f32_16x16x32_bf16(a[mf], b, acc1[mf][nf], 0, 0, 0);
      }
    }
  }

  // bias + relu -> hidden bf16 in LDS
  #pragma unroll
  for (int nf = 0; nf < 8; nf++) {
    int col = wid * 128 + nf * 16 + llo;
    float bb = b1[col];
    #pragma unroll
    for (int mf = 0; mf < 4; mf++) {
      #pragma unroll
      for (int r = 0; r < 4; r++) {
        float v = acc1[mf][nf][r] + bb;
        v = v > 0.f ? v : 0.f;
        hid[(mf * 16 + lhi * 4 + r) * HP + col] = f2bf(v);
      }
    }
  }
  __syncthreads();

  // ---------------- GEMM2: [64 x 512] @ [512 x 256] ----------------
  f32x4 acc2[4][4] = {};
  const bf16x8* bp2 = (const bf16x8*)w2p;
  #pragma unroll 4
  for (int kk = 0; kk < 512; kk += 32) {
    bf16x8 a[4];
    #pragma unroll
    for (int mf = 0; mf < 4; mf++)
      a[mf] = *(const bf16x8*)(hid + (mf * 16 + llo) * HP + kk + lhi * 8);
    int kg = (kk >> 3) + lhi;
    #pragma unroll
    for (int nf = 0; nf < 4; nf++) {
      bf16x8 b = bp2[(size_t)kg * 256 + wid * 64 + nf * 16 + llo];
      #pragma unroll
      for (int mf = 0; mf < 4; mf++)
        acc2[mf][nf] = __builtin_amdgcn_mfma_f32_16x16x32_bf16(a[mf], b, acc2[mf][nf], 0, 0, 0);
    }
  }
  __syncthreads();  // everyone done reading hid

  #pragma unroll
  for (int nf = 0; nf < 4; nf++) {
    int col = wid * 64 + nf * 16 + llo;
    float bb = b2[col];
    #pragma unroll
    for (int mf = 0; mf < 4; mf++) {
      #pragma unroll
      for (int r = 0; r < 4; r++)
        outt[(mf * 16 + lhi * 4 + r) * OP + col] = acc2[mf][nf][r] + bb;
    }
  }
  __syncthreads();

  // ---------------- LayerNorm + residual + store ----------------
  int r = tid >> 2;   // row 0..63
  int s = tid & 3;    // quarter 0..3 (64 cols each)
  const float* rowp = outt + r * OP + s * 64;
  float sum = 0.f, sq = 0.f;
  #pragma unroll 8
  for (int c = 0; c < 64; c++) { float v = rowp[c]; sum += v; sq += v * v; }
  sum += __shfl_xor(sum, 1); sq += __shfl_xor(sq, 1);
  sum += __shfl_xor(sum, 2); sq += __shfl_xor(sq, 2);
  float mu  = sum * (1.f / 256.f);
  float var = sq  * (1.f / 256.f) - mu * mu;
  float rs  = rsqrtf(var + 1e-5f);

  int grow = m0 + r;
  if (MODE == 1 && grow >= NNODE) return;
  const float* resid = (MODE == 0 ? ea : x) + (size_t)grow * DD + s * 64;
  float* op = out + (size_t)grow * DD + s * 64;

  const float4* resid4 = (const float4*)resid;
  const float4* gam4   = (const float4*)(gam + s * 64);
  const float4* bet4   = (const float4*)(bet + s * 64);
  float4* op4 = (float4*)op;
  #pragma unroll 4
  for (int c4 = 0; c4 < 16; c4++) {
    float4 rv = resid4[c4];
    float4 gv = gam4[c4];
    float4 bv = bet4[c4];
    float4 ov;
    ov.x = (rowp[c4*4+0] - mu) * rs * gv.x + bv.x + rv.x;
    ov.y = (rowp[c4*4+1] - mu) * rs * gv.y + bv.y + rv.y;
    ov.z = (rowp[c4*4+2] - mu) * rs * gv.z + bv.z + rv.z;
    ov.w = (rowp[c4*4+3] - mu) * rs * gv.w + bv.w + rv.w;
    op4[c4] = ov;
  }
}

extern "C" void kernel_launch(void* const* d_in, const int* in_sizes, int n_in,
                              void* d_out, int out_size, void* d_ws, size_t ws_size,
                              hipStream_t stream) {
  const float* x      = (const float*)d_in[0];
  const int*   ei     = (const int*)  d_in[1];
  const float* ea     = (const float*)d_in[2];
  const float* e_w1   = (const float*)d_in[3];
  const float* e_b1   = (const float*)d_in[4];
  const float* e_w2   = (const float*)d_in[5];
  const float* e_b2   = (const float*)d_in[6];
  const float* e_g    = (const float*)d_in[7];
  const float* e_beta = (const float*)d_in[8];
  const float* n_w1   = (const float*)d_in[9];
  const float* n_b1   = (const float*)d_in[10];
  const float* n_w2   = (const float*)d_in[11];
  const float* n_b2   = (const float*)d_in[12];
  const float* n_g    = (const float*)d_in[13];
  const float* n_beta = (const float*)d_in[14];

  float* out_x = (float*)d_out;                       // [N, 256]
  float* out_e = (float*)d_out + (size_t)NNODE * DD;  // [E, 256]

  char* w = (char*)d_ws;
  short* xb   = (short*)(w);                    // 5,120,000 B
  short* ew1p = (short*)(w + 5120000);          //   786,432 B
  short* nw1p = (short*)(w + 5906432);          //   524,288 B
  short* ew2p = (short*)(w + 6430720);          //   262,144 B
  short* nw2p = (short*)(w + 6692864);          //   262,144 B
  short* aggb = (short*)(w + 6955008);          // 5,120,000 B (bf16 agg)
  int*   deg  = (int*)  (w + 12075008);         //    40,960 B
  int*   cur  = (int*)  (w + 12115968);         //    40,960 B
  int*   rs   = (int*)  (w + 12156928);         //    40,976 B (NNODE+1)
  int*   csr  = (int*)  (w + 12197904);         //   640,000 B  -> total ~12.8 MB

  // zero deg + cursor (adjacent)
  hipMemsetAsync(deg, 0, 81920, stream);

  cast_x_kernel<<<(NNODE * DD + 255) / 256, 256, 0, stream>>>(x, xb, NNODE * DD);
  pack_w_kernel<<<(768 * 512 + 255) / 256, 256, 0, stream>>>(e_w1, ew1p, 768, 512);
  pack_w_kernel<<<(512 * 512 + 255) / 256, 256, 0, stream>>>(n_w1, nw1p, 512, 512);
  pack_w_kernel<<<(512 * 256 + 255) / 256, 256, 0, stream>>>(e_w2, ew2p, 512, 256);
  pack_w_kernel<<<(512 * 256 + 255) / 256, 256, 0, stream>>>(n_w2, nw2p, 512, 256);

  hist_kernel<<<(NEDGE + 255) / 256, 256, 0, stream>>>(ei, deg);
  scan_kernel<<<1, 256, 0, stream>>>(deg, rs);
  scatter_kernel<<<(NEDGE + 255) / 256, 256, 0, stream>>>(ei, rs, cur, csr);

  fused_mlp<0><<<NEDGE / 64, 256, 0, stream>>>(x, xb, ei, ea, nullptr,
                                               ew1p, e_b1, ew2p, e_b2, e_g, e_beta, out_e);
  agg_kernel<<<(NNODE + 3) / 4, 256, 0, stream>>>(out_e, rs, csr, aggb);
  fused_mlp<1><<<(NNODE + 63) / 64, 256, 0, stream>>>(x, xb, ei, ea, aggb,
                                                      nw1p, n_b1, nw2p, n_b2, n_g, n_beta, out_x);
}

// Round 3
// 532.618 us; speedup vs baseline: 4.2553x; 1.0393x over previous
//
#include <hip/hip_runtime.h>

#define NNODE 10000
#define NEDGE 160000
#define DD 256

using f32x4  = __attribute__((ext_vector_type(4))) float;
using bf16x8 = __attribute__((ext_vector_type(8))) short;
using u32x4  = __attribute__((ext_vector_type(4))) unsigned;

__device__ inline short f2bf(float f) {
  unsigned u = __float_as_uint(f);
  unsigned r = (u + 0x7fffu + ((u >> 16) & 1u)) >> 16;
  return (short)(unsigned short)r;
}

// packed f32 pair -> 2 bf16 (RNE), 1 instruction
__device__ inline unsigned pkbf(float a, float b) {
  unsigned r;
  asm("v_cvt_pk_bf16_f32 %0, %1, %2" : "=v"(r) : "v"(a), "v"(b));
  return r;
}

__global__ void cast_x_kernel(const float* __restrict__ x, short* __restrict__ xb, int total) {
  int i = blockIdx.x * 256 + threadIdx.x;
  if (i < total) xb[i] = f2bf(x[i]);
}

// pack w[K][N] (f32) -> p[(k>>3)][n][k&7] (bf16): lane fragment loads become contiguous 16B
__global__ void pack_w_kernel(const float* __restrict__ w, short* __restrict__ p, int K, int N) {
  int idx = blockIdx.x * 256 + threadIdx.x;
  if (idx >= K * N) return;
  int k = idx / N, n = idx - k * N;
  p[(size_t)(k >> 3) * N * 8 + (size_t)n * 8 + (k & 7)] = f2bf(w[idx]);
}

// ---------------- CSR build ----------------
__global__ void hist_kernel(const int* __restrict__ ei, int* __restrict__ deg) {
  int e = blockIdx.x * 256 + threadIdx.x;
  if (e < NEDGE) {
    int j = ei[NEDGE + e]; j = min(max(j, 0), NNODE - 1);
    atomicAdd(&deg[j], 1);
  }
}

__global__ void scan_kernel(const int* __restrict__ deg, int* __restrict__ row_start) {
  __shared__ int part[256];
  int t = threadIdx.x;
  const int CH = 40;  // 256*40 = 10240 >= NNODE
  int base = t * CH;
  int s = 0;
  for (int i = 0; i < CH; i++) {
    int idx = base + i;
    s += (idx < NNODE) ? deg[idx] : 0;
  }
  part[t] = s;
  __syncthreads();
  for (int off = 1; off < 256; off <<= 1) {
    int v = (t >= off) ? part[t - off] : 0;
    __syncthreads();
    part[t] += v;
    __syncthreads();
  }
  int run = (t == 0) ? 0 : part[t - 1];
  for (int i = 0; i < CH; i++) {
    int idx = base + i;
    if (idx < NNODE) { row_start[idx] = run; run += deg[idx]; }
  }
  if (t == 255) row_start[NNODE] = part[255];
}

__global__ void scatter_kernel(const int* __restrict__ ei, const int* __restrict__ row_start,
                               int* __restrict__ cursor, int* __restrict__ csr) {
  int e = blockIdx.x * 256 + threadIdx.x;
  if (e < NEDGE) {
    int j = ei[NEDGE + e]; j = min(max(j, 0), NNODE - 1);
    int p = atomicAdd(&cursor[j], 1);
    csr[row_start[j] + p] = e;
  }
}

// one wave per node: gather new_edge rows, sum fp32, store bf16 agg
__global__ __launch_bounds__(256) void agg_kernel(const float* __restrict__ out_e,
                                                  const int* __restrict__ row_start,
                                                  const int* __restrict__ csr,
                                                  short* __restrict__ aggb) {
  int node = blockIdx.x * 4 + (threadIdx.x >> 6);
  int lane = threadIdx.x & 63;
  if (node >= NNODE) return;
  int rs = row_start[node], re = row_start[node + 1];
  float4 acc = {0.f, 0.f, 0.f, 0.f};
  for (int k = rs; k < re; k++) {
    int eid = csr[k];
    float4 v = *(const float4*)(out_e + (size_t)eid * DD + lane * 4);
    acc.x += v.x; acc.y += v.y; acc.z += v.z; acc.w += v.w;
  }
  short4 o;
  o.x = f2bf(acc.x); o.y = f2bf(acc.y); o.z = f2bf(acc.z); o.w = f2bf(acc.w);
  *(short4*)(aggb + (size_t)node * DD + lane * 4) = o;
}

// MODE 0: edge (K1=768, A = x[i] | x[j] | ea, residual=ea)
// MODE 1: node (K1=512, A = x | agg(bf16), residual=x)
// GEMM1: A-fragments loaded per-lane DIRECTLY from global (L2/L3-hot), no LDS, no barriers.
// GEMM2: hidden staged in LDS (block-local product). LN: in-register stats + 2KB partial exchange.
template<int MODE>
__global__ __launch_bounds__(256, 2)
void fused_mlp(const float* __restrict__ x,
               const short* __restrict__ xb,
               const int*   __restrict__ ei,
               const float* __restrict__ ea,
               const short* __restrict__ aggb,
               const short* __restrict__ w1p,
               const float* __restrict__ b1,
               const short* __restrict__ w2p,
               const float* __restrict__ b2,
               const float* __restrict__ gam,
               const float* __restrict__ bet,
               float*       __restrict__ out)
{
  constexpr int K1 = (MODE == 0) ? 768 : 512;
  constexpr int NSTEP = K1 / 64;
  constexpr int HP = 520;  // hidden pitch (bf16): b128 reads tile all 32 banks -> conflict-free

  __shared__ __align__(16) short hid[64 * HP];  // 66,560 B
  __shared__ float pS[4][64];                   // per-wave partial sums
  __shared__ float pQ[4][64];                   // per-wave partial sum-of-squares

  const int tid  = threadIdx.x;
  const int lane = tid & 63;
  const int wid  = tid >> 6;   // 0..3
  const int m0   = blockIdx.x * 64;
  const int lhi  = lane >> 4;  // 0..3
  const int llo  = lane & 15;  // 0..15

  // per-lane A-row base pointers (row = mf*16 + llo)
  const short* pI[4]; const short* pJ[4]; const float* pE[4];
  #pragma unroll
  for (int mf = 0; mf < 4; mf++) {
    int rowg = m0 + mf * 16 + llo;
    if (MODE == 0) {
      int ii = ei[rowg];         ii = min(max(ii, 0), NNODE - 1);
      int jj = ei[NEDGE + rowg]; jj = min(max(jj, 0), NNODE - 1);
      pI[mf] = xb + (size_t)ii * DD;
      pJ[mf] = xb + (size_t)jj * DD;
      pE[mf] = ea + (size_t)rowg * DD;
    } else {
      int rr = min(rowg, NNODE - 1);
      pI[mf] = xb + (size_t)rr * DD;
      pJ[mf] = aggb + (size_t)rr * DD;
      pE[mf] = nullptr;
    }
  }

  // ---------------- GEMM1: [64 x K1] @ [K1 x 512], registers only ----------------
  f32x4 acc1[4][8] = {};
  const bf16x8* bp1 = (const bf16x8*)w1p;
  const int bcol1 = wid * 128 + llo;

  #pragma unroll
  for (int s = 0; s < NSTEP; s++) {
    #pragma unroll
    for (int kk = 0; kk < 64; kk += 32) {
      const int ko = s * 64 + kk + lhi * 8;  // global k of this 8-wide fragment
      bf16x8 a[4];
      #pragma unroll
      for (int mf = 0; mf < 4; mf++) {
        if (MODE == 0) {
          if (s < 4)      a[mf] = *(const bf16x8*)(pI[mf] + ko);
          else if (s < 8) a[mf] = *(const bf16x8*)(pJ[mf] + (ko - 256));
          else {
            const float* fp = pE[mf] + (ko - 512);
            float4 u0 = *(const float4*)fp;
            float4 u1 = *(const float4*)(fp + 4);
            u32x4 q = { pkbf(u0.x, u0.y), pkbf(u0.z, u0.w),
                        pkbf(u1.x, u1.y), pkbf(u1.z, u1.w) };
            a[mf] = __builtin_bit_cast(bf16x8, q);
          }
        } else {
          if (s < 4) a[mf] = *(const bf16x8*)(pI[mf] + ko);
          else       a[mf] = *(const bf16x8*)(pJ[mf] + (ko - 256));
        }
      }
      const bf16x8* bbase = bp1 + (size_t)(((s * 64 + kk) >> 3) + lhi) * 512 + bcol1;
      #pragma unroll
      for (int nf = 0; nf < 8; nf++) {
        bf16x8 b = bbase[nf * 16];
        #pragma unroll
        for (int mf = 0; mf < 4; mf++)
          acc1[mf][nf] = __builtin_amdgcn_mfma_f32_16x16x32_bf16(a[mf], b, acc1[mf][nf], 0, 0, 0);
      }
    }
  }

  // bias + relu -> hidden bf16 in LDS
  #pragma unroll
  for (int nf = 0; nf < 8; nf++) {
    int col = wid * 128 + nf * 16 + llo;
    float bb = b1[col];
    #pragma unroll
    for (int mf = 0; mf < 4; mf++) {
      #pragma unroll
      for (int r = 0; r < 4; r++) {
        float v = acc1[mf][nf][r] + bb;
        v = v > 0.f ? v : 0.f;
        hid[(mf * 16 + lhi * 4 + r) * HP + col] = f2bf(v);
      }
    }
  }
  __syncthreads();

  // ---------------- GEMM2: [64 x 512] @ [512 x 256] ----------------
  f32x4 acc2[4][4] = {};
  const bf16x8* bp2 = (const bf16x8*)w2p;
  const int bcol2 = wid * 64 + llo;
  #pragma unroll
  for (int kk = 0; kk < 512; kk += 32) {
    bf16x8 a[4];
    #pragma unroll
    for (int mf = 0; mf < 4; mf++)
      a[mf] = *(const bf16x8*)(hid + (mf * 16 + llo) * HP + kk + lhi * 8);
    const bf16x8* bbase = bp2 + (size_t)((kk >> 3) + lhi) * 256 + bcol2;
    #pragma unroll
    for (int nf = 0; nf < 4; nf++) {
      bf16x8 b = bbase[nf * 16];
      #pragma unroll
      for (int mf = 0; mf < 4; mf++)
        acc2[mf][nf] = __builtin_amdgcn_mfma_f32_16x16x32_bf16(a[mf], b, acc2[mf][nf], 0, 0, 0);
    }
  }

  // ---------------- LayerNorm in registers ----------------
  float bb2[4], gg[4], be[4];
  #pragma unroll
  for (int nf = 0; nf < 4; nf++) {
    int col = bcol2 + nf * 16;
    bb2[nf] = b2[col]; gg[nf] = gam[col]; be[nf] = bet[col];
  }
  #pragma unroll
  for (int mf = 0; mf < 4; mf++)
    #pragma unroll
    for (int nf = 0; nf < 4; nf++)
      #pragma unroll
      for (int r = 0; r < 4; r++)
        acc2[mf][nf][r] += bb2[nf];

  // per-lane partial stats for its 16 (mf,r) rows over its 4 nf cols
  float S[4][4], Q[4][4];
  #pragma unroll
  for (int mf = 0; mf < 4; mf++) {
    #pragma unroll
    for (int r = 0; r < 4; r++) {
      float s = 0.f, q = 0.f;
      #pragma unroll
      for (int nf = 0; nf < 4; nf++) {
        float v = acc2[mf][nf][r];
        s += v; q += v * v;
      }
      S[mf][r] = s; Q[mf][r] = q;
    }
  }
  // reduce over the 16 llo lanes (same row)
  #pragma unroll
  for (int m = 1; m <= 8; m <<= 1) {
    #pragma unroll
    for (int mf = 0; mf < 4; mf++)
      #pragma unroll
      for (int r = 0; r < 4; r++) {
        S[mf][r] += __shfl_xor(S[mf][r], m);
        Q[mf][r] += __shfl_xor(Q[mf][r], m);
      }
  }
  if (llo == 0) {
    #pragma unroll
    for (int mf = 0; mf < 4; mf++)
      #pragma unroll
      for (int r = 0; r < 4; r++) {
        int row = mf * 16 + lhi * 4 + r;
        pS[wid][row] = S[mf][r];
        pQ[wid][row] = Q[mf][r];
      }
  }
  __syncthreads();

  float mu[4][4], rsv[4][4];
  #pragma unroll
  for (int mf = 0; mf < 4; mf++) {
    #pragma unroll
    for (int r = 0; r < 4; r++) {
      int row = mf * 16 + lhi * 4 + r;
      float s = pS[0][row] + pS[1][row] + pS[2][row] + pS[3][row];
      float q = pQ[0][row] + pQ[1][row] + pQ[2][row] + pQ[3][row];
      float m_ = s * (1.f / 256.f);
      mu[mf][r]  = m_;
      rsv[mf][r] = rsqrtf(q * (1.f / 256.f) - m_ * m_ + 1e-5f);
    }
  }

  // ---------------- normalize + residual + store ----------------
  const float* resb = (MODE == 0) ? ea : x;
  #pragma unroll
  for (int mf = 0; mf < 4; mf++) {
    #pragma unroll
    for (int r = 0; r < 4; r++) {
      int grow = m0 + mf * 16 + lhi * 4 + r;
      if (MODE == 1 && grow >= NNODE) continue;
      const float* rp = resb + (size_t)grow * DD + bcol2;
      float*       op = out  + (size_t)grow * DD + bcol2;
      #pragma unroll
      for (int nf = 0; nf < 4; nf++) {
        float v = (acc2[mf][nf][r] - mu[mf][r]) * rsv[mf][r] * gg[nf] + be[nf] + rp[nf * 16];
        op[nf * 16] = v;
      }
    }
  }
}

extern "C" void kernel_launch(void* const* d_in, const int* in_sizes, int n_in,
                              void* d_out, int out_size, void* d_ws, size_t ws_size,
                              hipStream_t stream) {
  const float* x      = (const float*)d_in[0];
  const int*   ei     = (const int*)  d_in[1];
  const float* ea     = (const float*)d_in[2];
  const float* e_w1   = (const float*)d_in[3];
  const float* e_b1   = (const float*)d_in[4];
  const float* e_w2   = (const float*)d_in[5];
  const float* e_b2   = (const float*)d_in[6];
  const float* e_g    = (const float*)d_in[7];
  const float* e_beta = (const float*)d_in[8];
  const float* n_w1   = (const float*)d_in[9];
  const float* n_b1   = (const float*)d_in[10];
  const float* n_w2   = (const float*)d_in[11];
  const float* n_b2   = (const float*)d_in[12];
  const float* n_g    = (const float*)d_in[13];
  const float* n_beta = (const float*)d_in[14];

  float* out_x = (float*)d_out;                       // [N, 256]
  float* out_e = (float*)d_out + (size_t)NNODE * DD;  // [E, 256]

  char* w = (char*)d_ws;
  short* xb   = (short*)(w);                    // 5,120,000 B
  short* ew1p = (short*)(w + 5120000);          //   786,432 B
  short* nw1p = (short*)(w + 5906432);          //   524,288 B
  short* ew2p = (short*)(w + 6430720);          //   262,144 B
  short* nw2p = (short*)(w + 6692864);          //   262,144 B
  short* aggb = (short*)(w + 6955008);          // 5,120,000 B (bf16 agg)
  int*   deg  = (int*)  (w + 12075008);         //    40,960 B
  int*   cur  = (int*)  (w + 12115968);         //    40,960 B
  int*   rs   = (int*)  (w + 12156928);         //    40,976 B (NNODE+1)
  int*   csr  = (int*)  (w + 12197904);         //   640,000 B  -> total ~12.8 MB

  hipMemsetAsync(deg, 0, 81920, stream);  // deg + cursor (adjacent)

  cast_x_kernel<<<(NNODE * DD + 255) / 256, 256, 0, stream>>>(x, xb, NNODE * DD);
  pack_w_kernel<<<(768 * 512 + 255) / 256, 256, 0, stream>>>(e_w1, ew1p, 768, 512);
  pack_w_kernel<<<(512 * 512 + 255) / 256, 256, 0, stream>>>(n_w1, nw1p, 512, 512);
  pack_w_kernel<<<(512 * 256 + 255) / 256, 256, 0, stream>>>(e_w2, ew2p, 512, 256);
  pack_w_kernel<<<(512 * 256 + 255) / 256, 256, 0, stream>>>(n_w2, nw2p, 512, 256);

  hist_kernel<<<(NEDGE + 255) / 256, 256, 0, stream>>>(ei, deg);
  scan_kernel<<<1, 256, 0, stream>>>(deg, rs);
  scatter_kernel<<<(NEDGE + 255) / 256, 256, 0, stream>>>(ei, rs, cur, csr);

  fused_mlp<0><<<NEDGE / 64, 256, 0, stream>>>(x, xb, ei, ea, aggb,
                                               ew1p, e_b1, ew2p, e_b2, e_g, e_beta, out_e);
  agg_kernel<<<(NNODE + 3) / 4, 256, 0, stream>>>(out_e, rs, csr, aggb);
  fused_mlp<1><<<(NNODE + 63) / 64, 256, 0, stream>>>(x, xb, ei, ea, aggb,
                                                      nw1p, n_b1, nw2p, n_b2, n_g, n_beta, out_x);
}